// Round 5
// baseline (306.366 us; speedup 1.0000x reference)
//
#include <hip/hip_runtime.h>

// snnTorch Leaky recurrence, reset='subtract':
//   mem_t = 0.95*mem_{t-1} + x_t - spk_{t-1};  spk_t = (mem_t > 1)
// N=8192 independent chains, T=4000 sequential.
//
// R4 post-mortem: per-wave global_load_lds ops SERIALIZE at ~230 cyc each
// (LDS base rides in M0 -> s_mov m0 per row -> drain of in-flight DMA before
// each rewrite). Buffering depth is irrelevant; 64 DMAs/tile/wave = 14.7K
// cyc/tile stall. Fix: (1) 16 neurons/wave (512 waves, 2 blocks/CU) -> only
// 16 DMAs/tile/wave; (2) interleave ONE DMA per 4 compute columns (~200 cyc
// of chain work between issues) so each DMA's round trip hides under compute.
// Spikes stay bit-packed (R4: WRITE 131->4.3 MB); expand kernel unchanged.
//
// Numerics: exact reference rounding ((0.95*mem + x) - r) via __f*_rn, no
// fma contraction — verified absmax 0.0 in R1-R4.

namespace {

constexpr int T_LEN = 4000;
constexpr int N_NEU = 8192;
constexpr int RPW   = 16;               // neurons (rows) per wave
constexpr int TT    = 256;              // steps per full tile (1 KB per row)
constexpr int CT    = TT / 4;           // 64 float4 cols per row-tile
constexpr int NFT   = 15;               // full tiles
constexpr int TAILC = (T_LEN - NFT * TT) / 4;  // 40 float4 cols (160 steps)
constexpr int RS    = 65;               // LDS row stride (float4): 1040 B slot
                                        // covers the 1024 B DMA landing; odd
                                        // stride = conflict-free (R2-R4: 0)
constexpr int QROW  = 128;              // packed row stride in u32
constexpr size_t QBYTES = (size_t)N_NEU * QROW * 4;  // 4 MiB scratch

__device__ __forceinline__ unsigned step1(float x, float& mem, float& r) {
    float t = __fmul_rn(0.95f, mem);
    t       = __fadd_rn(t, x);
    mem     = __fsub_rn(t, r);
    bool s  = mem > 1.0f;
    r = s ? 1.0f : 0.0f;      // spike_t == reset_{t+1}
    return s ? 1u : 0u;
}

// Compute C float4-cols of this wave's tile (lane -> LDS row l&15; lanes
// 16..63 duplicate = same-address broadcast reads). If PREFETCH, issue one
// async DMA for row (c>>2) of the NEXT tile every 4th column — spacing the
// M0 rewrites ~200 chain-cycles apart so their drains are already satisfied.
template <int C, int W, bool PREFETCH>
__device__ __forceinline__ void compute_tile(const float4* __restrict__ buf,
                                             int lrow,
                                             const float* __restrict__ nsrc,
                                             float4* __restrict__ nbuf,
                                             float& mem, float& r,
                                             unsigned* __restrict__ qrow,
                                             bool qen) {
    const float4* irow = buf + lrow * RS;
    unsigned u[W];
#pragma unroll
    for (int w = 0; w < W; ++w) u[w] = 0;
#pragma unroll
    for (int c = 0; c < C; ++c) {
        if (PREFETCH && (c & 3) == 0 && (c >> 2) < RPW) {
            const int k = c >> 2;      // next-tile row k -> nbuf row k
            __builtin_amdgcn_global_load_lds(
                (const __attribute__((address_space(1))) void*)(nsrc + (size_t)k * T_LEN),
                (__attribute__((address_space(3))) void*)&nbuf[k * RS], 16, 0, 0);
        }
        float4 v = irow[c];
        unsigned b;
        b  = step1(v.x, mem, r);
        b |= step1(v.y, mem, r) << 1;
        b |= step1(v.z, mem, r) << 2;
        b |= step1(v.w, mem, r) << 3;
        u[c >> 3] |= b << ((c & 7) * 4);
    }
    if (qen) {
        if (W == 8) {
            *reinterpret_cast<uint4*>(qrow)     = make_uint4(u[0], u[1], u[2], u[3]);
            *reinterpret_cast<uint4*>(qrow + 4) = make_uint4(u[4], u[5], u[6], u[7]);
        } else {  // W == 5 (tail)
            *reinterpret_cast<uint4*>(qrow) = make_uint4(u[0], u[1], u[2], u[3]);
            qrow[4] = u[4];
        }
    }
}

__global__ __launch_bounds__(64, 1)
void snn_scan(const float* __restrict__ x, unsigned* __restrict__ q) {
    __shared__ float4 bufA[RPW * RS];    // 16640 B
    __shared__ float4 bufB[RPW * RS];    // 16640 B (33280/block, 2 blocks/CU)
    const int l    = threadIdx.x;
    const int lrow = l & (RPW - 1);
    const size_t n0 = (size_t)blockIdx.x * RPW;
    const float* xb = x + n0 * T_LEN;
    unsigned* qn = q + (n0 + lrow) * QROW;
    const bool qen = (l < RPW);

    // Per-lane global column pointers. Tail tile is 640 B/row; lanes >= 40
    // clamp to col 39 (duplicate reads; landing stays inside the 1040 B slot,
    // never past row 8191's data).
    const int lc = (l < TAILC) ? l : (TAILC - 1);
    const float* xtail = xb + NFT * TT + lc * 4;

    float mem = 0.0f;   // mem_0 = 0
    float r   = 0.0f;   // reset_1 = H(0-1) = 0

    // Prologue: stage tile 0 into A (16 serialized DMAs, ~4K cyc, once).
#pragma unroll
    for (int k = 0; k < RPW; ++k)
        __builtin_amdgcn_global_load_lds(
            (const __attribute__((address_space(1))) void*)(xb + l * 4 + (size_t)k * T_LEN),
            (__attribute__((address_space(3))) void*)&bufA[k * RS], 16, 0, 0);

    int t = 0;
#pragma unroll 1
    for (int d = 0; d < 7; ++d) {   // tiles 0..13 in ping-pong pairs
        compute_tile<CT, 8, true>(bufA, lrow, xb + (t + 1) * TT + l * 4, bufB,
                                  mem, r, qn + t * 8, qen);
        compute_tile<CT, 8, true>(bufB, lrow, xb + (t + 2) * TT + l * 4, bufA,
                                  mem, r, qn + (t + 1) * 8, qen);
        t += 2;
    }
    // t == 14: compute tile 14 from A, prefetch tail into B, then tail.
    compute_tile<CT, 8, true>(bufA, lrow, xtail, bufB, mem, r, qn + 14 * 8, qen);
    compute_tile<TAILC, 5, false>(bufB, lrow, nullptr, nullptr,
                                  mem, r, qn + 15 * 8, qen);
}

// Expand packed bits -> float spikes, fully coalesced float4 writes.
// 8192*1000 float4s = 32000 blocks x 256 threads exactly. (R4: ~20 us,
// near the write roofline.)
__global__ __launch_bounds__(256)
void snn_expand(const unsigned* __restrict__ q, float* __restrict__ out) {
    const unsigned i = blockIdx.x * 256 + threadIdx.x;  // float4 index
    const unsigned n = i / 1000u;                       // neuron row
    const unsigned c = i - n * 1000u;                   // float4 col
    const unsigned w = q[n * QROW + (c >> 3)];
    const unsigned nib = w >> ((c & 7u) * 4u);
    float4 f;
    f.x = (nib & 1u) ? 1.0f : 0.0f;
    f.y = (nib & 2u) ? 1.0f : 0.0f;
    f.z = (nib & 4u) ? 1.0f : 0.0f;
    f.w = (nib & 8u) ? 1.0f : 0.0f;
    reinterpret_cast<float4*>(out)[i] = f;
}

} // namespace

extern "C" void kernel_launch(void* const* d_in, const int* in_sizes, int n_in,
                              void* d_out, int out_size, void* d_ws, size_t ws_size,
                              hipStream_t stream) {
    const float* x = (const float*)d_in[0];
    float* out     = (float*)d_out;
    unsigned* q    = (unsigned*)d_ws;   // R4 verified ws_size >= 4 MiB path taken
    snn_scan<<<dim3(N_NEU / RPW), dim3(64), 0, stream>>>(x, q);
    snn_expand<<<dim3(32000), dim3(256), 0, stream>>>(q, out);
}